// Round 1
// baseline (2760.550 us; speedup 1.0000x reference)
//
#include <hip/hip_runtime.h>
#include <hip/hip_bf16.h>
#include <stdint.h>

// Problem constants (from reference)
#define NQ    32768      // BATCH*SEQ
#define DIM   256
#define KCB   8192       // codebook size

// Main-kernel tiling
#define TQ    64         // queries per block
#define XPAD  260        // x LDS row stride (floats): 2-way-only bank aliasing, 16B aligned
#define KC    64         // codewords per chunk
#define DK    32         // dims per staged slice
#define CPAD  36         // c LDS row stride (floats): 2-way-only bank aliasing, 16B aligned

// ---------------------------------------------------------------------------
// Kernel 0: codebook squared norms -> csq[KCB]
// ---------------------------------------------------------------------------
__global__ __launch_bounds__(256) void vq_csq(const float* __restrict__ cb,
                                              float* __restrict__ csq) {
  const int w    = threadIdx.x >> 6;       // wave within block (0..3)
  const int lane = threadIdx.x & 63;
  const int row  = blockIdx.x * 4 + w;     // grid = KCB/4
  float4 v = ((const float4*)(cb + (size_t)row * DIM))[lane];
  float s = v.x * v.x + v.y * v.y + v.z * v.z + v.w * v.w;
  #pragma unroll
  for (int m = 32; m >= 1; m >>= 1) s += __shfl_xor(s, m, 64);
  if (lane == 0) csq[row] = s;
}

// ---------------------------------------------------------------------------
// Kernel 1: fused distance + argmin. dist = csq[c] - 2*dot(x,c)
// (x_sq is per-query constant; argmin-invariant.)
// Block: 256 threads = 16(tx) x 16(ty). Tile: 64 queries x all 8192 codewords.
// Thread (tx,ty) handles queries {ty+16i} and codewords {kc0+tx+16j}.
// ---------------------------------------------------------------------------
__global__ __launch_bounds__(256, 2) void vq_main(const float* __restrict__ x,
                                                  const float* __restrict__ cb,
                                                  const float* __restrict__ csq,
                                                  float* __restrict__ out_idx) {
  __shared__ float xs[TQ * XPAD];   // 66560 B
  __shared__ float cs[KC * CPAD];   //  9216 B

  const int tid = threadIdx.x;
  const int tx  = tid & 15;
  const int ty  = tid >> 4;
  const int q0  = blockIdx.x * TQ;

  // Stage x tile: 64 rows x 256 floats = 4096 float4, 16 per thread (coalesced).
  #pragma unroll
  for (int k = 0; k < 16; ++k) {
    int e   = tid + k * 256;     // float4 index in tile
    int row = e >> 6;            // 64 float4 per row
    int c4  = e & 63;
    float4 v = ((const float4*)(x + (size_t)(q0 + row) * DIM))[c4];
    *(float4*)&xs[row * XPAD + c4 * 4] = v;
  }

  float best[4];
  int   bidx[4];
  #pragma unroll
  for (int i = 0; i < 4; ++i) { best[i] = 3.402823466e38f; bidx[i] = 0; }

  for (int kc0 = 0; kc0 < KCB; kc0 += KC) {
    float acc[4][4];
    #pragma unroll
    for (int i = 0; i < 4; ++i)
      #pragma unroll
      for (int j = 0; j < 4; ++j) acc[i][j] = 0.0f;

    for (int d0 = 0; d0 < DIM; d0 += DK) {
      __syncthreads();  // protect cs from previous iteration's readers
      // Stage c slice: 64 rows x 32 floats = 512 float4, 2 per thread.
      #pragma unroll
      for (int k = 0; k < 2; ++k) {
        int e   = tid + k * 256;
        int row = e >> 3;        // 8 float4 per row
        int c4  = e & 7;
        float4 v = ((const float4*)(cb + (size_t)(kc0 + row) * DIM + d0))[c4];
        *(float4*)&cs[row * CPAD + c4 * 4] = v;
      }
      __syncthreads();

      #pragma unroll
      for (int d4 = 0; d4 < DK; d4 += 4) {
        float4 qf[4], cf[4];
        #pragma unroll
        for (int i = 0; i < 4; ++i)
          qf[i] = *(const float4*)&xs[(ty + 16 * i) * XPAD + d0 + d4];
        #pragma unroll
        for (int j = 0; j < 4; ++j)
          cf[j] = *(const float4*)&cs[(tx + 16 * j) * CPAD + d4];
        #pragma unroll
        for (int i = 0; i < 4; ++i)
          #pragma unroll
          for (int j = 0; j < 4; ++j)
            acc[i][j] += qf[i].x * cf[j].x + qf[i].y * cf[j].y +
                         qf[i].z * cf[j].z + qf[i].w * cf[j].w;
      }
    }

    // Fold chunk into running argmin. j ascending => codeword index ascending,
    // strict < keeps first occurrence (numpy tie-break).
    #pragma unroll
    for (int j = 0; j < 4; ++j) {
      int   cidx = kc0 + tx + 16 * j;
      float cs2  = csq[cidx];
      #pragma unroll
      for (int i = 0; i < 4; ++i) {
        float d = cs2 - 2.0f * acc[i][j];
        if (d < best[i]) { best[i] = d; bidx[i] = cidx; }
      }
    }
  }

  // Reduce across the 16 tx lanes sharing each query (within one wave).
  #pragma unroll
  for (int i = 0; i < 4; ++i) {
    float b  = best[i];
    int   bi = bidx[i];
    #pragma unroll
    for (int m = 8; m >= 1; m >>= 1) {
      float ob  = __shfl_xor(b, m, 64);
      int   obi = __shfl_xor(bi, m, 64);
      if (ob < b || (ob == b && obi < bi)) { b = ob; bi = obi; }
    }
    if (tx == 0) out_idx[q0 + ty + 16 * i] = (float)bi;  // indices as fp32
  }
}

// ---------------------------------------------------------------------------
// Kernel 2: gather codebook rows per argmin index.
// One wave per query: 64 lanes x float4 = 256 floats.
// ---------------------------------------------------------------------------
__global__ __launch_bounds__(256) void vq_gather(const float* __restrict__ cb,
                                                 const float* __restrict__ idxf,
                                                 float* __restrict__ outq) {
  const int q    = blockIdx.x * 4 + (threadIdx.x >> 6);
  const int lane = threadIdx.x & 63;
  const int idx  = (int)idxf[q];
  float4 v = ((const float4*)(cb + (size_t)idx * DIM))[lane];
  ((float4*)(outq + (size_t)q * DIM))[lane] = v;
}

// ---------------------------------------------------------------------------
extern "C" void kernel_launch(void* const* d_in, const int* in_sizes, int n_in,
                              void* d_out, int out_size, void* d_ws, size_t ws_size,
                              hipStream_t stream) {
  const float* x  = (const float*)d_in[0];   // [NQ, DIM]
  const float* cb = (const float*)d_in[1];   // [KCB, DIM]
  float* out      = (float*)d_out;           // [NQ] indices ++ [NQ*DIM] quantized

  // csq lives at the head of the quantized output region; vq_main consumes it,
  // vq_gather overwrites it afterwards (stream-ordered). No d_ws dependence.
  float* csq  = out + NQ;
  float* outq = out + NQ;

  vq_csq  <<<KCB / 4, 256, 0, stream>>>(cb, csq);
  vq_main <<<NQ / TQ, 256, 0, stream>>>(x, cb, csq, out);
  vq_gather<<<NQ / 4, 256, 0, stream>>>(cb, out, outq);
}

// Round 2
// 711.989 us; speedup vs baseline: 3.8772x; 3.8772x over previous
//
#include <hip/hip_runtime.h>
#include <stdint.h>

// Problem constants
#define NQ    32768      // BATCH*SEQ
#define DIM   256
#define KCB   8192       // codebook size

// Main-kernel tiling
#define TQ      64       // queries per block
#define CCHUNK 256       // codewords per chunk (4 waves x 64)
#define WC      64       // codewords per wave
#define DK      32       // K-slice per MFMA step
#define RS      40       // LDS row stride in fp16 (32 + 8 pad = 80B -> 2-way-only banks)
#define LOSCALE     2048.0f
#define INV_LOSCALE (1.0f / 2048.0f)

typedef _Float16 f16;
typedef f16  v8h __attribute__((ext_vector_type(8)));
typedef f16  v4h __attribute__((ext_vector_type(4)));
typedef float v4f __attribute__((ext_vector_type(4)));

// ---------------------------------------------------------------------------
// Prep: codebook fp32 -> fp16 hi + fp16 lo*2048, plus squared norms.
// One wave per codebook row. Grid = KCB/4.
// ---------------------------------------------------------------------------
__global__ __launch_bounds__(256) void vq_prep(const float* __restrict__ cb,
                                               float* __restrict__ csq,
                                               f16* __restrict__ cbh,
                                               f16* __restrict__ cbl) {
  const int w    = threadIdx.x >> 6;
  const int lane = threadIdx.x & 63;
  const int row  = blockIdx.x * 4 + w;
  float4 v = ((const float4*)(cb + (size_t)row * DIM))[lane];
  v4h h, l;
  h.x = (f16)v.x; l.x = (f16)((v.x - (float)h.x) * LOSCALE);
  h.y = (f16)v.y; l.y = (f16)((v.y - (float)h.y) * LOSCALE);
  h.z = (f16)v.z; l.z = (f16)((v.z - (float)h.z) * LOSCALE);
  h.w = (f16)v.w; l.w = (f16)((v.w - (float)h.w) * LOSCALE);
  *(v4h*)&cbh[(size_t)row * DIM + lane * 4] = h;
  *(v4h*)&cbl[(size_t)row * DIM + lane * 4] = l;
  float s = v.x * v.x + v.y * v.y + v.z * v.z + v.w * v.w;
  #pragma unroll
  for (int m = 32; m >= 1; m >>= 1) s += __shfl_xor(s, m, 64);
  if (lane == 0) csq[row] = s;
}

// ---------------------------------------------------------------------------
// Main: fused distance GEMM (fp16x3 MFMA) + argmin.
// dist = csq[c] - 2*dot(x,c); dot = acc1 + acc2/2048.
// Block: 256 thr = 4 waves. Block tile: 64 q x 256-c chunks.
// Wave wv covers codewords [c0 + wv*64, +64): 4x4 tiles of 16x16x32 f16 MFMA.
// A-frag: x[m=lane&15][k=quad*8+j]; B-frag: cb[n=lane&15][k=quad*8+j];
// D: row(query)=quad*4+reg, col(codeword)=lane&15.   [m89-verified layouts]
// ---------------------------------------------------------------------------
__global__ __launch_bounds__(256, 2) void vq_main(const float* __restrict__ x,
                                                  const float* __restrict__ csq,
                                                  const f16* __restrict__ cbh,
                                                  const f16* __restrict__ cbl,
                                                  float* __restrict__ out_idx) {
  __shared__ f16 xh[TQ * RS];       //  5120 B
  __shared__ f16 xl[TQ * RS];       //  5120 B
  __shared__ f16 ch[CCHUNK * RS];   // 20480 B
  __shared__ f16 cl[CCHUNK * RS];   // 20480 B   total 51200 B -> 2 blocks/CU

  const int tid  = threadIdx.x;
  const int lane = tid & 63;
  const int wv   = tid >> 6;          // wave = codeword group within chunk
  const int q0   = blockIdx.x * TQ;
  const int n    = lane & 15;
  const int quad = lane >> 4;

  float best[4][4];                    // [it][reg]
  int   bidx[4][4];
  #pragma unroll
  for (int i = 0; i < 4; ++i)
    #pragma unroll
    for (int r = 0; r < 4; ++r) { best[i][r] = 3.402823466e38f; bidx[i][r] = 0; }

  for (int c0 = 0; c0 < KCB; c0 += CCHUNK) {
    v4f acc1[4][4], acc2[4][4];        // [it][jt]
    #pragma unroll
    for (int i = 0; i < 4; ++i)
      #pragma unroll
      for (int j = 0; j < 4; ++j) {
        acc1[i][j] = (v4f){0.f, 0.f, 0.f, 0.f};
        acc2[i][j] = (v4f){0.f, 0.f, 0.f, 0.f};
      }

    for (int d0 = 0; d0 < DIM; d0 += DK) {
      __syncthreads();   // protect LDS from previous iteration's readers

      // Stage x slice: 64 q x 32 d -> fp16 hi/lo (on-the-fly split).
      #pragma unroll
      for (int k2 = 0; k2 < 2; ++k2) {
        int f   = tid + k2 * 256;     // 512 float4s
        int row = f >> 3, c4 = f & 7;
        float4 v = *(const float4*)(x + (size_t)(q0 + row) * DIM + d0 + c4 * 4);
        v4h h, l;
        h.x = (f16)v.x; l.x = (f16)((v.x - (float)h.x) * LOSCALE);
        h.y = (f16)v.y; l.y = (f16)((v.y - (float)h.y) * LOSCALE);
        h.z = (f16)v.z; l.z = (f16)((v.z - (float)h.z) * LOSCALE);
        h.w = (f16)v.w; l.w = (f16)((v.w - (float)h.w) * LOSCALE);
        *(v4h*)&xh[row * RS + c4 * 4] = h;
        *(v4h*)&xl[row * RS + c4 * 4] = l;
      }
      // Stage cb slice: 256 c x 32 d, pre-split fp16 (straight copy).
      #pragma unroll
      for (int k4 = 0; k4 < 4; ++k4) {
        int u   = tid + k4 * 256;     // 1024 16B-units per array
        int row = u >> 2, c16 = u & 3;
        size_t g = (size_t)(c0 + row) * DIM + d0 + c16 * 8;
        v8h hv = *(const v8h*)(cbh + g);
        v8h lv = *(const v8h*)(cbl + g);
        *(v8h*)&ch[row * RS + c16 * 8] = hv;
        *(v8h*)&cl[row * RS + c16 * 8] = lv;
      }
      __syncthreads();

      // A fragments (shared across jt)
      v8h a_h[4], a_l[4];
      #pragma unroll
      for (int it = 0; it < 4; ++it) {
        int r = it * 16 + n;
        a_h[it] = *(const v8h*)&xh[r * RS + quad * 8];
        a_l[it] = *(const v8h*)&xl[r * RS + quad * 8];
      }
      #pragma unroll
      for (int jt = 0; jt < 4; ++jt) {
        int r = wv * WC + jt * 16 + n;
        v8h b_h = *(const v8h*)&ch[r * RS + quad * 8];
        v8h b_l = *(const v8h*)&cl[r * RS + quad * 8];
        #pragma unroll
        for (int it = 0; it < 4; ++it) {
          acc1[it][jt] = __builtin_amdgcn_mfma_f32_16x16x32_f16(a_h[it], b_h, acc1[it][jt], 0, 0, 0);
          acc2[it][jt] = __builtin_amdgcn_mfma_f32_16x16x32_f16(a_h[it], b_l, acc2[it][jt], 0, 0, 0);
          acc2[it][jt] = __builtin_amdgcn_mfma_f32_16x16x32_f16(a_l[it], b_h, acc2[it][jt], 0, 0, 0);
        }
      }
    }

    // Chunk epilogue: fold into running argmin. jt ascending + strict '<'
    // preserves first-occurrence (lowest index) tie-break within a lane.
    #pragma unroll
    for (int jt = 0; jt < 4; ++jt) {
      int   cidx = c0 + wv * WC + jt * 16 + n;
      float cs2  = csq[cidx];
      #pragma unroll
      for (int it = 0; it < 4; ++it)
        #pragma unroll
        for (int r = 0; r < 4; ++r) {
          float d = cs2 - 2.0f * (acc1[it][jt][r] + acc2[it][jt][r] * INV_LOSCALE);
          if (d < best[it][r]) { best[it][r] = d; bidx[it][r] = cidx; }
        }
    }
  }

  // Final reduction. First across the 16 codeword lanes (xor 1,2,4,8 stays
  // within the quad's 16-lane group), lexicographic (dist, idx).
  __syncthreads();                       // all waves done reading xh/xl
  float* redd = (float*)xh;              // 256 floats (per wave x per query)
  int*   redi = (int*)xl;
  #pragma unroll
  for (int it = 0; it < 4; ++it)
    #pragma unroll
    for (int r = 0; r < 4; ++r) {
      float b  = best[it][r];
      int   bi = bidx[it][r];
      #pragma unroll
      for (int m = 8; m >= 1; m >>= 1) {
        float ob  = __shfl_xor(b, m, 64);
        int   obi = __shfl_xor(bi, m, 64);
        if (ob < b || (ob == b && obi < bi)) { b = ob; bi = obi; }
      }
      if (n == 0) {
        int q = it * 16 + quad * 4 + r;
        redd[wv * TQ + q] = b;
        redi[wv * TQ + q] = bi;
      }
    }
  __syncthreads();
  // Cross-wave (4 codeword groups) per query; lex (d, idx) keeps np tie-break.
  if (tid < TQ) {
    float b  = redd[tid];
    int   bi = redi[tid];
    #pragma unroll
    for (int w = 1; w < 4; ++w) {
      float ob  = redd[w * TQ + tid];
      int   obi = redi[w * TQ + tid];
      if (ob < b || (ob == b && obi < bi)) { b = ob; bi = obi; }
    }
    out_idx[q0 + tid] = (float)bi;       // indices as fp32 (validated in R1)
  }
}

// ---------------------------------------------------------------------------
// Gather codebook rows per argmin index. One wave per query.
// ---------------------------------------------------------------------------
__global__ __launch_bounds__(256) void vq_gather(const float* __restrict__ cb,
                                                 const float* __restrict__ idxf,
                                                 float* __restrict__ outq) {
  const int q    = blockIdx.x * 4 + (threadIdx.x >> 6);
  const int lane = threadIdx.x & 63;
  const int idx  = (int)idxf[q];
  float4 v = ((const float4*)(cb + (size_t)idx * DIM))[lane];
  ((float4*)(outq + (size_t)q * DIM))[lane] = v;
}

// ---------------------------------------------------------------------------
extern "C" void kernel_launch(void* const* d_in, const int* in_sizes, int n_in,
                              void* d_out, int out_size, void* d_ws, size_t ws_size,
                              hipStream_t stream) {
  const float* x  = (const float*)d_in[0];   // [NQ, DIM]
  const float* cb = (const float*)d_in[1];   // [KCB, DIM]
  float* out      = (float*)d_out;           // [NQ] indices ++ [NQ*DIM] quantized

  // Scratch lives in the quantized-output region (33.5 MB): csq (32 KB) +
  // cbh/cbl fp16 (8.4 MB). vq_main consumes it; vq_gather overwrites it
  // afterwards (stream-ordered). No d_ws dependence.
  float* P    = out + NQ;
  float* csq  = P;                           // [KCB] fp32
  f16*   cbh  = (f16*)(P + KCB);             // [KCB*DIM] fp16
  f16*   cbl  = cbh + (size_t)KCB * DIM;     // [KCB*DIM] fp16
  float* outq = out + NQ;

  vq_prep  <<<KCB / 4, 256, 0, stream>>>(cb, csq, cbh, cbl);
  vq_main  <<<NQ / TQ, 256, 0, stream>>>(x, csq, cbh, cbl, out);
  vq_gather<<<NQ / 4, 256, 0, stream>>>(cb, out, outq);
}

// Round 3
// 497.294 us; speedup vs baseline: 5.5511x; 1.4317x over previous
//
#include <hip/hip_runtime.h>
#include <stdint.h>

// Problem constants
#define NQ    32768      // BATCH*SEQ
#define DIM   256
#define KCB   8192       // codebook size

// Stage-1 tiling
#define TQ      64       // queries per block
#define CCHUNK 256       // codewords per chunk (4 waves x 64)
#define NCHUNK (KCB / CCHUNK)   // 32
#define NKS    (NCHUNK * 8)     // 256 flattened K-steps
#define T_MARGIN 0.25f   // approx top-2 gap threshold (worst est. err ~0.08)

typedef _Float16 f16;
typedef f16   v8h __attribute__((ext_vector_type(8)));
typedef f16   v4h __attribute__((ext_vector_type(4)));
typedef float v4f __attribute__((ext_vector_type(4)));
typedef const __attribute__((address_space(1))) uint32_t* gas_p;
typedef __attribute__((address_space(3))) uint32_t*       las_p;

// Scratch layout (float offsets) in the quantized-output region P = out + NQ
// (8.39M floats; all overwritten by vq_gather at the end).
#define OFF_CSQ   0               // [KCB] fp32
#define OFF_CBT   8192            // [KCB*DIM] f16, tiled+swizzled (1.05M floats)
#define OFF_CNT   1114112         // 1 int
#define OFF_LIST  1114116         // [NQ] int
#define OFF_CELL  1179648         // [NQ] u64 (8B-aligned: 4718592 bytes)

// ---------------------------------------------------------------------------
// Prep: codebook fp32 -> f16, tiled [chunk][slice][row 0..255][unit swizzled],
// where unit u (8 halves) sits at physical slot u ^ ((row>>1)&3). Also csq
// (fp32 squared norms) and zero the flag counter. One wave per codebook row.
// ---------------------------------------------------------------------------
__global__ __launch_bounds__(256) void vq_prep(const float* __restrict__ cb,
                                               float* __restrict__ csq,
                                               f16* __restrict__ cbt,
                                               int* __restrict__ cnt) {
  if (blockIdx.x == 0 && threadIdx.x == 0) *cnt = 0;
  const int w     = threadIdx.x >> 6;
  const int lane  = threadIdx.x & 63;
  const int c     = blockIdx.x * 4 + w;      // grid = KCB/4
  const int chunk = c >> 8, r = c & 255;
  const int g = lane >> 1, h = lane & 1;     // unit g (16B), half h (8B)
  const int s = g >> 2, u = g & 3;           // slice s (32 dims), unit u
  float4 v = *(const float4*)(cb + (size_t)c * DIM + s * 32 + u * 8 + h * 4);
  v4h hv;
  hv[0] = (f16)v.x; hv[1] = (f16)v.y; hv[2] = (f16)v.z; hv[3] = (f16)v.w;
  const int up = u ^ ((r >> 1) & 3);
  *(v4h*)(cbt + (size_t)chunk * 65536 + s * 8192 + r * 32 + up * 8 + h * 4) = hv;
  float sq = v.x * v.x + v.y * v.y + v.z * v.z + v.w * v.w;
  #pragma unroll
  for (int m = 32; m >= 1; m >>= 1) sq += __shfl_xor(sq, m, 64);
  if (lane == 0) csq[c] = sq;
}

// ---------------------------------------------------------------------------
// Stage 1: f16-hi-only distance GEMM + per-query approx top-2.
// x tile LDS-resident (swizzled); cb slices double-buffered via
// global_load_lds (verbatim copy of the pre-swizzled tile image).
// A-frag x[m=lane&15][k=quad*8+j], B-frag cb[n=lane&15][k], D row=quad*4+r,
// col=lane&15 (R2-validated conventions).
// ---------------------------------------------------------------------------
__global__ __launch_bounds__(256, 2) void vq_stage1(
    const float* __restrict__ x, const float* __restrict__ csq,
    const f16* __restrict__ cbt, float* __restrict__ out_idx,
    int* __restrict__ cnt, int* __restrict__ list,
    unsigned long long* __restrict__ cell) {
  __shared__ f16 xh[8 * 64 * 32];      // 8 slices x 64 q x 32 halves = 32 KB
  __shared__ f16 ch[2][CCHUNK * 32];   // 2 x 16 KB double buffer

  const int tid  = threadIdx.x;
  const int lane = tid & 63;
  const int wv   = tid >> 6;
  const int q0   = blockIdx.x * TQ;
  const int n    = lane & 15;
  const int quad = lane >> 4;
  const int usel = quad ^ ((n >> 1) & 3);   // physical frag unit (swizzle)

  // Issue one 256x32 cb slice (16 KB) into ch[buf]: 4 waves x 4 x 1024 B.
  auto issue = [&](int nk, int buf) {
    const int chunk = nk >> 3, s = nk & 7;
    #pragma unroll
    for (int i = 0; i < 4; ++i) {
      const f16* gp = cbt + (size_t)chunk * 65536 + s * 8192 + wv * 2048 +
                      i * 512 + lane * 8;
      f16* lp = &ch[buf][wv * 2048 + i * 512];   // wave-uniform base
      __builtin_amdgcn_global_load_lds((gas_p)gp, (las_p)lp, 16, 0, 0);
    }
  };

  issue(0, 0);   // start DMA of chunk0/slice0 under the x load

  // Load x tile once: 64 q x 256 d fp32 -> f16, swizzled. 2048 units.
  #pragma unroll
  for (int k = 0; k < 8; ++k) {
    int e = tid + k * 256;
    int u = e & 3, q = (e >> 2) & 63, s = e >> 8;
    const float* gp = x + (size_t)(q0 + q) * DIM + s * 32 + u * 8;
    float4 a = *(const float4*)gp;
    float4 b = *(const float4*)(gp + 4);
    v8h hv;
    hv[0] = (f16)a.x; hv[1] = (f16)a.y; hv[2] = (f16)a.z; hv[3] = (f16)a.w;
    hv[4] = (f16)b.x; hv[5] = (f16)b.y; hv[6] = (f16)b.z; hv[7] = (f16)b.w;
    int up = u ^ ((q >> 1) & 3);
    *(v8h*)&xh[s * 2048 + q * 32 + up * 8] = hv;
  }

  float bd1[4][4], bd2[4][4];
  int   bi1[4][4], bi2[4][4];
  #pragma unroll
  for (int it = 0; it < 4; ++it)
    #pragma unroll
    for (int r = 0; r < 4; ++r) {
      bd1[it][r] = 3.402823466e38f; bd2[it][r] = 3.402823466e38f;
      bi1[it][r] = 0; bi2[it][r] = 0;
    }

  for (int chunk = 0; chunk < NCHUNK; ++chunk) {
    v4f acc[4][4];
    #pragma unroll
    for (int it = 0; it < 4; ++it)
      #pragma unroll
      for (int jt = 0; jt < 4; ++jt) acc[it][jt] = (v4f){0.f, 0.f, 0.f, 0.f};

    #pragma unroll
    for (int s = 0; s < 8; ++s) {
      __syncthreads();                       // current buf ready (vmcnt drained)
      const int ks = chunk * 8 + s;
      if (ks + 1 < NKS) issue(ks + 1, (ks + 1) & 1);
      const int buf = ks & 1;

      v8h af[4];
      #pragma unroll
      for (int it = 0; it < 4; ++it)
        af[it] = *(const v8h*)&xh[s * 2048 + (it * 16 + n) * 32 + usel * 8];
      #pragma unroll
      for (int jt = 0; jt < 4; ++jt) {
        v8h bf = *(const v8h*)&ch[buf][(wv * 64 + jt * 16 + n) * 32 + usel * 8];
        #pragma unroll
        for (int it = 0; it < 4; ++it)
          acc[it][jt] = __builtin_amdgcn_mfma_f32_16x16x32_f16(
              af[it], bf, acc[it][jt], 0, 0, 0);
      }
    }

    // Chunk epilogue: fold into per-lane top-2 (ascending cidx + strict '<'
    // keeps first occurrence).
    #pragma unroll
    for (int jt = 0; jt < 4; ++jt) {
      int   cidx = chunk * CCHUNK + wv * 64 + jt * 16 + n;
      float cs2  = csq[cidx];
      #pragma unroll
      for (int it = 0; it < 4; ++it)
        #pragma unroll
        for (int r = 0; r < 4; ++r) {
          float d = cs2 - 2.0f * acc[it][jt][r];
          if (d < bd1[it][r]) {
            bd2[it][r] = bd1[it][r]; bi2[it][r] = bi1[it][r];
            bd1[it][r] = d;          bi1[it][r] = cidx;
          } else if (d < bd2[it][r]) {
            bd2[it][r] = d; bi2[it][r] = cidx;
          }
        }
    }
  }

  // Merge top-2 across the 16 column lanes (xor 1..8 stays in-group).
  __syncthreads();                           // all LDS compute reads done
  float* rd1 = (float*)&ch[0][0];            // reuse ch as reduction scratch
  float* rd2 = rd1 + 256;
  int*   ri1 = (int*)(rd2 + 256);
  int*   ri2 = ri1 + 256;
  #pragma unroll
  for (int it = 0; it < 4; ++it)
    #pragma unroll
    for (int r = 0; r < 4; ++r) {
      float d1 = bd1[it][r], d2 = bd2[it][r];
      int   i1 = bi1[it][r], i2 = bi2[it][r];
      #pragma unroll
      for (int m = 1; m <= 8; m <<= 1) {
        float od1 = __shfl_xor(d1, m, 64), od2 = __shfl_xor(d2, m, 64);
        int   oi1 = __shfl_xor(i1, m, 64), oi2 = __shfl_xor(i2, m, 64);
        bool  lt  = (od1 < d1) || (od1 == d1 && oi1 < i1);
        float w1  = lt ? od1 : d1;  int wi1 = lt ? oi1 : i1;
        float l1  = lt ? d1  : od1; int li1 = lt ? i1  : oi1;
        float c2  = lt ? od2 : d2;  int ci2 = lt ? oi2 : i2;
        bool  lt2 = (l1 < c2) || (l1 == c2 && li1 < ci2);
        d1 = w1; i1 = wi1;
        d2 = lt2 ? l1 : c2; i2 = lt2 ? li1 : ci2;
      }
      if (n == 0) {
        int q = it * 16 + quad * 4 + r;
        rd1[wv * 64 + q] = d1; ri1[wv * 64 + q] = i1;
        rd2[wv * 64 + q] = d2; ri2[wv * 64 + q] = i2;
      }
    }
  __syncthreads();

  // Cross-wave merge (4 codeword groups) and flagging.
  if (tid < TQ) {
    float d1 = rd1[tid], d2 = rd2[tid];
    int   i1 = ri1[tid], i2 = ri2[tid];
    #pragma unroll
    for (int w = 1; w < 4; ++w) {
      float od1 = rd1[w * 64 + tid], od2 = rd2[w * 64 + tid];
      int   oi1 = ri1[w * 64 + tid], oi2 = ri2[w * 64 + tid];
      bool  lt  = (od1 < d1) || (od1 == d1 && oi1 < i1);
      float w1  = lt ? od1 : d1;  int wi1 = lt ? oi1 : i1;
      float l1  = lt ? d1  : od1; int li1 = lt ? i1  : oi1;
      float c2  = lt ? od2 : d2;  int ci2 = lt ? oi2 : i2;
      bool  lt2 = (l1 < c2) || (l1 == c2 && li1 < ci2);
      d1 = w1; i1 = wi1;
      d2 = lt2 ? l1 : c2; i2 = lt2 ? li1 : ci2;
    }
    out_idx[q0 + tid] = (float)i1;
    if (d2 - d1 <= T_MARGIN) {     // can't certify argmin from approx -> exact
      int p = atomicAdd(cnt, 1);
      list[p] = q0 + tid;
      cell[q0 + tid] = 0xFFFFFFFFFFFFFFFFULL;
    }
  }
}

// ---------------------------------------------------------------------------
// Stage 2: exact fp32 re-rank of flagged queries. Work item = (group of 8
// flagged queries, 1024-codeword range). Lex (d, idx) via packed-u64
// atomicMin == numpy first-occurrence argmin.
// ---------------------------------------------------------------------------
__global__ __launch_bounds__(256) void vq_rerank(
    const float* __restrict__ x, const float* __restrict__ cb,
    const float* __restrict__ csq, const int* __restrict__ cnt,
    const int* __restrict__ list, unsigned long long* __restrict__ cell) {
  __shared__ float xs[8 * 256];
  __shared__ int qs[8];
  __shared__ unsigned long long red[32];
  const int count = *cnt;
  if (count == 0) return;
  const int ngroups = (count + 7) >> 3;
  const int total   = ngroups * 8;
  const int tid = threadIdx.x, lane = tid & 63, wv = tid >> 6;

  for (int w = blockIdx.x; w < total; w += gridDim.x) {
    const int g = w >> 3, cc = w & 7;
    __syncthreads();
    if (tid < 8) {
      int slot = g * 8 + tid;
      qs[tid] = list[slot < count ? slot : count - 1];  // pad with dup (safe)
    }
    __syncthreads();
    #pragma unroll
    for (int k = 0; k < 2; ++k) {
      int f = tid + k * 256, j = f >> 6, c4 = f & 63;
      *(float4*)&xs[j * 256 + c4 * 4] =
          *(const float4*)(x + (size_t)qs[j] * DIM + c4 * 4);
    }
    __syncthreads();

    float bestd[8]; int besti[8];
    #pragma unroll
    for (int j = 0; j < 8; ++j) { bestd[j] = 3.402823466e38f; besti[j] = 0; }
    for (int b = 0; b < 4; ++b) {
      const int r = cc * 1024 + b * 256 + tid;
      float accq[8];
      #pragma unroll
      for (int j = 0; j < 8; ++j) accq[j] = 0.f;
      for (int d4 = 0; d4 < 64; ++d4) {
        float4 cf = *(const float4*)(cb + (size_t)r * DIM + d4 * 4);
        #pragma unroll
        for (int j = 0; j < 8; ++j) {
          float4 xf = *(const float4*)&xs[j * 256 + d4 * 4];  // broadcast read
          accq[j] += xf.x * cf.x + xf.y * cf.y + xf.z * cf.z + xf.w * cf.w;
        }
      }
      float cs2 = csq[r];
      #pragma unroll
      for (int j = 0; j < 8; ++j) {
        float d = cs2 - 2.f * accq[j];
        if (d < bestd[j]) { bestd[j] = d; besti[j] = r; }   // r ascending
      }
    }
    #pragma unroll
    for (int j = 0; j < 8; ++j) {
      unsigned int ub = __float_as_uint(bestd[j]);
      ub ^= (ub >> 31) ? 0xFFFFFFFFu : 0x80000000u;   // sortable float key
      unsigned long long key =
          ((unsigned long long)ub << 32) | (unsigned)besti[j];
      #pragma unroll
      for (int m = 32; m >= 1; m >>= 1) {
        unsigned long long o = __shfl_xor(key, m, 64);
        if (o < key) key = o;
      }
      if (lane == 0) red[wv * 8 + j] = key;
    }
    __syncthreads();
    if (tid < 8) {
      unsigned long long key = red[tid];
      #pragma unroll
      for (int v = 1; v < 4; ++v) {
        unsigned long long o = red[v * 8 + tid];
        if (o < key) key = o;
      }
      atomicMin(&cell[qs[tid]], key);
    }
    __syncthreads();
  }
}

// ---------------------------------------------------------------------------
// Fix-up: write re-ranked indices for flagged queries.
// ---------------------------------------------------------------------------
__global__ __launch_bounds__(256) void vq_fix(const int* __restrict__ cnt,
                                              const int* __restrict__ list,
                                              const unsigned long long* __restrict__ cell,
                                              float* __restrict__ out_idx) {
  const int count = *cnt;
  for (int i = blockIdx.x * 256 + threadIdx.x; i < count;
       i += gridDim.x * 256) {
    int q = list[i];
    out_idx[q] = (float)(unsigned)(cell[q] & 0xFFFFFFFFu);
  }
}

// ---------------------------------------------------------------------------
// Gather codebook rows per final index. One wave per query.
// ---------------------------------------------------------------------------
__global__ __launch_bounds__(256) void vq_gather(const float* __restrict__ cb,
                                                 const float* __restrict__ idxf,
                                                 float* __restrict__ outq) {
  const int q    = blockIdx.x * 4 + (threadIdx.x >> 6);
  const int lane = threadIdx.x & 63;
  const int idx  = (int)idxf[q];
  float4 v = ((const float4*)(cb + (size_t)idx * DIM))[lane];
  ((float4*)(outq + (size_t)q * DIM))[lane] = v;
}

// ---------------------------------------------------------------------------
extern "C" void kernel_launch(void* const* d_in, const int* in_sizes, int n_in,
                              void* d_out, int out_size, void* d_ws, size_t ws_size,
                              hipStream_t stream) {
  const float* x  = (const float*)d_in[0];   // [NQ, DIM]
  const float* cb = (const float*)d_in[1];   // [KCB, DIM]
  float* out      = (float*)d_out;           // [NQ] idx ++ [NQ*DIM] quantized

  float* P = out + NQ;                       // scratch region (gather rewrites)
  float* csq = P + OFF_CSQ;
  f16*   cbt = (f16*)(P + OFF_CBT);
  int*   cnt = (int*)(P + OFF_CNT);
  int*   lst = (int*)(P + OFF_LIST);
  unsigned long long* cel = (unsigned long long*)(P + OFF_CELL);
  float* outq = P;

  vq_prep  <<<KCB / 4, 256, 0, stream>>>(cb, csq, cbt, cnt);
  vq_stage1<<<NQ / TQ, 256, 0, stream>>>(x, csq, cbt, out, cnt, lst, cel);
  vq_rerank<<<512,     256, 0, stream>>>(x, cb, csq, cnt, lst, cel);
  vq_fix   <<<32,      256, 0, stream>>>(cnt, lst, cel, out);
  vq_gather<<<NQ / 4,  256, 0, stream>>>(cb, out, outq);
}